// Round 2
// 374.427 us; speedup vs baseline: 1.0051x; 1.0051x over previous
//
#include <hip/hip_runtime.h>
#include <math.h>

#define C_IN  512
#define WDIM  128

// ---------------- wave-wide sum: DPP within 16, swizzle/bpermute across ----------------
// (proven in the 376.3us baseline — unchanged)
__device__ __forceinline__ float wave_sum(float v) {
    int t;
    // row_ror:8  — lane i += lane (i+8)%16 within its row of 16
    t = __builtin_amdgcn_update_dpp(0, __float_as_int(v), 0x128, 0xF, 0xF, true);
    v += __int_as_float(t);
    // row_ror:4
    t = __builtin_amdgcn_update_dpp(0, __float_as_int(v), 0x124, 0xF, 0xF, true);
    v += __int_as_float(t);
    // quad_perm [2,3,0,1] = xor2
    t = __builtin_amdgcn_update_dpp(0, __float_as_int(v), 0x4E, 0xF, 0xF, true);
    v += __int_as_float(t);
    // quad_perm [1,0,3,2] = xor1
    t = __builtin_amdgcn_update_dpp(0, __float_as_int(v), 0xB1, 0xF, 0xF, true);
    v += __int_as_float(t);
    // xor16 via ds_swizzle (BitMode: offset = xor<<10 | and 0x1F)
    v += __int_as_float(__builtin_amdgcn_ds_swizzle(__float_as_int(v), 0x401F));
    // cross-32 half (ds_bpermute across full wave64)
    v += __shfl_xor(v, 32, 64);
    return v;
}

__device__ __forceinline__ float fast_tanh(float x) {
    // tanh(x) = 1 - 2/(e^{2x}+1); exact at +/-inf, ~1e-6 rel error (threshold 2e-2)
    float e = __expf(2.0f * x);
    return 1.0f - 2.0f / (e + 1.0f);
}

// ---------------- Fused kernel ----------------
// Phase 1: block recomputes its image's effective 1x1 kernel (512 x 4) into LDS,
//          plane-major keS[out][cin]. aw (256 KB) is L2/L3-resident after first touch;
//          redundant reads (2048 blocks x 256 KB = 512 MB) stay well under L2
//          aggregate BW and hide under the HBM stream of x.
// Phase 2: wave-per-16-pixels, split-K over lanes. Lane l owns channels
//          [4l..4l+3] and [256+4l..256+4l+3]: the two x float4 loads per pixel are
//          each a contiguous 1 KiB wave transaction.
__global__ __launch_bounds__(256) void torgb_fused(
    const float* __restrict__ x, const float* __restrict__ w,
    const float* __restrict__ aw, const float* __restrict__ ab,
    const float* __restrict__ k2d, const float* __restrict__ bias,
    float* __restrict__ out)
{
    __shared__ __align__(16) float keS[4][C_IN];   // [c_out][c_in], 8 KB

    const int tid = threadIdx.x;
    const int b   = blockIdx.x >> 8;               // 256 blocks per image (64 px each)

    // ---- Phase 1: effective kernel for this image -> LDS ----
    {
        const float* __restrict__ wr = w + b * WDIM;   // wave-uniform row
        const int c0 = tid, c1 = tid + 256;
        float s0 = 0.f, s1 = 0.f;
        #pragma unroll 8
        for (int j = 0; j < WDIM; ++j) {
            const float wj = wr[j];
            s0 = fmaf(wj, aw[j * C_IN + c0], s0);      // coalesced across lanes
            s1 = fmaf(wj, aw[j * C_IN + c1], s1);
        }
        s0 = (s0 + ab[c0]) * 0.04419417382415922f;     // 1/sqrt(512)
        s1 = (s1 + ab[c1]) * 0.04419417382415922f;
        const float4 kk0 = ((const float4*)k2d)[c0];
        const float4 kk1 = ((const float4*)k2d)[c1];
        keS[0][c0] = s0 * kk0.x; keS[1][c0] = s0 * kk0.y;
        keS[2][c0] = s0 * kk0.z; keS[3][c0] = s0 * kk0.w;
        keS[0][c1] = s1 * kk1.x; keS[1][c1] = s1 * kk1.y;
        keS[2][c1] = s1 * kk1.z; keS[3][c1] = s1 * kk1.w;
    }
    __syncthreads();

    const int lane = tid & 63;
    // Per-lane fragments: ka[o] = ke[o][4l..4l+3], kb[o] = ke[o][256+4l..256+4l+3]
    float4 ka[4], kb[4];
    #pragma unroll
    for (int o = 0; o < 4; ++o) {
        ka[o] = ((const float4*)&keS[o][0])[lane];
        kb[o] = ((const float4*)&keS[o][256])[lane];
    }
    const float4 bb = *(const float4*)bias;
    float4* __restrict__ out4 = (float4*)out;

    const int wave_g   = (blockIdx.x << 2) | (tid >> 6);   // 4 waves/block
    const int pix_base = wave_g << 4;                      // 16 px per wave

    #pragma unroll 2
    for (int i = 0; i < 16; ++i) {
        const int pix = pix_base + i;
        const float4* __restrict__ xp = (const float4*)(x + (size_t)pix * C_IN);
        const float4 xa = xp[lane];        // coalesced: bytes [16l .. 16l+15] of row
        const float4 xb = xp[64 + lane];   // coalesced: second KiB of row

        float a0, a1, a2, a3;
        a0 = fmaf(xa.x, ka[0].x, fmaf(xa.y, ka[0].y, fmaf(xa.z, ka[0].z, xa.w * ka[0].w)));
        a1 = fmaf(xa.x, ka[1].x, fmaf(xa.y, ka[1].y, fmaf(xa.z, ka[1].z, xa.w * ka[1].w)));
        a2 = fmaf(xa.x, ka[2].x, fmaf(xa.y, ka[2].y, fmaf(xa.z, ka[2].z, xa.w * ka[2].w)));
        a3 = fmaf(xa.x, ka[3].x, fmaf(xa.y, ka[3].y, fmaf(xa.z, ka[3].z, xa.w * ka[3].w)));
        a0 = fmaf(xb.x, kb[0].x, fmaf(xb.y, kb[0].y, fmaf(xb.z, kb[0].z, fmaf(xb.w, kb[0].w, a0))));
        a1 = fmaf(xb.x, kb[1].x, fmaf(xb.y, kb[1].y, fmaf(xb.z, kb[1].z, fmaf(xb.w, kb[1].w, a1))));
        a2 = fmaf(xb.x, kb[2].x, fmaf(xb.y, kb[2].y, fmaf(xb.z, kb[2].z, fmaf(xb.w, kb[2].w, a2))));
        a3 = fmaf(xb.x, kb[3].x, fmaf(xb.y, kb[3].y, fmaf(xb.z, kb[3].z, fmaf(xb.w, kb[3].w, a3))));

        a0 = wave_sum(a0);
        a1 = wave_sum(a1);
        a2 = wave_sum(a2);
        a3 = wave_sum(a3);

        if (lane == 0) {
            float4 o;
            o.x = fast_tanh(a0 + bb.x);
            o.y = fast_tanh(a1 + bb.y);
            o.z = fast_tanh(a2 + bb.z);
            o.w = fast_tanh(a3 + bb.w);
            out4[pix] = o;
        }
    }
}

extern "C" void kernel_launch(void* const* d_in, const int* in_sizes, int n_in,
                              void* d_out, int out_size, void* d_ws, size_t ws_size,
                              hipStream_t stream) {
    const float* x    = (const float*)d_in[0];   // [8,128,128,512]
    const float* w    = (const float*)d_in[1];   // [8,128]
    const float* aw   = (const float*)d_in[2];   // [128,512]
    const float* ab   = (const float*)d_in[3];   // [512]
    const float* kk   = (const float*)d_in[4];   // [1,1,512,4]
    const float* bias = (const float*)d_in[5];   // [4]
    float* out = (float*)d_out;                  // [8,128,128,4] fp32
    (void)d_ws; (void)ws_size;

    // 131072 pixels / (16 px/wave * 4 waves/block) = 2048 blocks, single fused kernel
    hipLaunchKernelGGL(torgb_fused, dim3(2048), dim3(256), 0, stream,
                       x, w, aw, ab, kk, bias, out);
}

// Round 3
// 369.809 us; speedup vs baseline: 1.0176x; 1.0125x over previous
//
#include <hip/hip_runtime.h>
#include <math.h>

#define C_IN  512
#define WDIM  128

// ---------------- wave-wide sum: DPP within 16, swizzle/bpermute across ----------------
// (proven in the 376.3us baseline — unchanged)
__device__ __forceinline__ float wave_sum(float v) {
    int t;
    // row_ror:8  — lane i += lane (i+8)%16 within its row of 16
    t = __builtin_amdgcn_update_dpp(0, __float_as_int(v), 0x128, 0xF, 0xF, true);
    v += __int_as_float(t);
    // row_ror:4
    t = __builtin_amdgcn_update_dpp(0, __float_as_int(v), 0x124, 0xF, 0xF, true);
    v += __int_as_float(t);
    // quad_perm [2,3,0,1] = xor2
    t = __builtin_amdgcn_update_dpp(0, __float_as_int(v), 0x4E, 0xF, 0xF, true);
    v += __int_as_float(t);
    // quad_perm [1,0,3,2] = xor1
    t = __builtin_amdgcn_update_dpp(0, __float_as_int(v), 0xB1, 0xF, 0xF, true);
    v += __int_as_float(t);
    // xor16 via ds_swizzle (BitMode: offset = xor<<10 | and 0x1F)
    v += __int_as_float(__builtin_amdgcn_ds_swizzle(__float_as_int(v), 0x401F));
    // cross-32 half (ds_bpermute across full wave64)
    v += __shfl_xor(v, 32, 64);
    return v;
}

__device__ __forceinline__ float fast_tanh(float x) {
    // tanh(x) = 1 - 2/(e^{2x}+1); exact at +/-inf, ~1e-6 rel error (threshold 2e-2)
    float e = __expf(2.0f * x);
    return 1.0f - 2.0f / (e + 1.0f);
}

// ---------------- Fused kernel, 1024-thread blocks ----------------
// 512 blocks x 1024 threads (16 waves). Phase-1 aw redundancy: 512 x 256 KB
// = 128 MB of L2 reads (was 512 MB with 2048 blocks) -> ~4 us burst instead of ~15.
// Phase 1: threads split the 128-row dot in halves (64 rows each), combine via LDS.
// Phase 2: identical wave-per-16-pixels split-K structure as before.
__global__ __launch_bounds__(1024) void torgb_fused(
    const float* __restrict__ x, const float* __restrict__ w,
    const float* __restrict__ aw, const float* __restrict__ ab,
    const float* __restrict__ k2d, const float* __restrict__ bias,
    float* __restrict__ out)
{
    __shared__ __align__(16) float keS[4][C_IN];   // [c_out][c_in], 8 KB
    __shared__ float pS[2 * C_IN];                 // partial dots, 4 KB

    const int tid = threadIdx.x;
    const int b   = blockIdx.x >> 6;               // 64 blocks per image (256 px each)

    // ---- Phase 1: effective kernel for this image -> LDS ----
    {
        const int h = tid >> 9;                    // row-half: 0 or 1
        const int c = tid & 511;                   // channel
        const float* __restrict__ wr = w + b * WDIM + h * 64;   // wave-uniform
        const float* __restrict__ ap = aw + (size_t)(h * 64) * C_IN + c;
        float s = 0.f;
        #pragma unroll 8
        for (int j = 0; j < 64; ++j)
            s = fmaf(wr[j], ap[j * C_IN], s);      // coalesced across lanes
        pS[h * C_IN + c] = s;
    }
    __syncthreads();
    if (tid < C_IN) {
        const float s = (pS[tid] + pS[C_IN + tid] + ab[tid]) * 0.04419417382415922f; // 1/sqrt(512)
        const float4 kk = ((const float4*)k2d)[tid];
        keS[0][tid] = s * kk.x; keS[1][tid] = s * kk.y;
        keS[2][tid] = s * kk.z; keS[3][tid] = s * kk.w;
    }
    __syncthreads();

    const int lane = tid & 63;
    // Per-lane fragments: ka[o] = ke[o][4l..4l+3], kb[o] = ke[o][256+4l..256+4l+3]
    float4 ka[4], kb[4];
    #pragma unroll
    for (int o = 0; o < 4; ++o) {
        ka[o] = ((const float4*)&keS[o][0])[lane];
        kb[o] = ((const float4*)&keS[o][256])[lane];
    }
    const float4 bb = *(const float4*)bias;
    float4* __restrict__ out4 = (float4*)out;

    const int wave_g   = (blockIdx.x << 4) | (tid >> 6);   // 16 waves/block
    const int pix_base = wave_g << 4;                      // 16 px per wave

    #pragma unroll 2
    for (int i = 0; i < 16; ++i) {
        const int pix = pix_base + i;
        const float4* __restrict__ xp = (const float4*)(x + (size_t)pix * C_IN);
        const float4 xa = xp[lane];        // coalesced: bytes [16l .. 16l+15] of row
        const float4 xb = xp[64 + lane];   // coalesced: second KiB of row

        float a0, a1, a2, a3;
        a0 = fmaf(xa.x, ka[0].x, fmaf(xa.y, ka[0].y, fmaf(xa.z, ka[0].z, xa.w * ka[0].w)));
        a1 = fmaf(xa.x, ka[1].x, fmaf(xa.y, ka[1].y, fmaf(xa.z, ka[1].z, xa.w * ka[1].w)));
        a2 = fmaf(xa.x, ka[2].x, fmaf(xa.y, ka[2].y, fmaf(xa.z, ka[2].z, xa.w * ka[2].w)));
        a3 = fmaf(xa.x, ka[3].x, fmaf(xa.y, ka[3].y, fmaf(xa.z, ka[3].z, xa.w * ka[3].w)));
        a0 = fmaf(xb.x, kb[0].x, fmaf(xb.y, kb[0].y, fmaf(xb.z, kb[0].z, fmaf(xb.w, kb[0].w, a0))));
        a1 = fmaf(xb.x, kb[1].x, fmaf(xb.y, kb[1].y, fmaf(xb.z, kb[1].z, fmaf(xb.w, kb[1].w, a1))));
        a2 = fmaf(xb.x, kb[2].x, fmaf(xb.y, kb[2].y, fmaf(xb.z, kb[2].z, fmaf(xb.w, kb[2].w, a2))));
        a3 = fmaf(xb.x, kb[3].x, fmaf(xb.y, kb[3].y, fmaf(xb.z, kb[3].z, fmaf(xb.w, kb[3].w, a3))));

        a0 = wave_sum(a0);
        a1 = wave_sum(a1);
        a2 = wave_sum(a2);
        a3 = wave_sum(a3);

        if (lane == 0) {
            float4 o;
            o.x = fast_tanh(a0 + bb.x);
            o.y = fast_tanh(a1 + bb.y);
            o.z = fast_tanh(a2 + bb.z);
            o.w = fast_tanh(a3 + bb.w);
            out4[pix] = o;
        }
    }
}

extern "C" void kernel_launch(void* const* d_in, const int* in_sizes, int n_in,
                              void* d_out, int out_size, void* d_ws, size_t ws_size,
                              hipStream_t stream) {
    const float* x    = (const float*)d_in[0];   // [8,128,128,512]
    const float* w    = (const float*)d_in[1];   // [8,128]
    const float* aw   = (const float*)d_in[2];   // [128,512]
    const float* ab   = (const float*)d_in[3];   // [512]
    const float* kk   = (const float*)d_in[4];   // [1,1,512,4]
    const float* bias = (const float*)d_in[5];   // [4]
    float* out = (float*)d_out;                  // [8,128,128,4] fp32
    (void)d_ws; (void)ws_size;

    // 131072 pixels / (16 px/wave * 16 waves/block) = 512 blocks
    hipLaunchKernelGGL(torgb_fused, dim3(512), dim3(1024), 0, stream,
                       x, w, aw, ab, kk, bias, out);
}